// Round 2
// baseline (364.196 us; speedup 1.0000x reference)
//
#include <hip/hip_runtime.h>
#include <math.h>

#define EDIM 100
#define NF 4000
#define NN 4000
#define NB 8
#define FT 80      // number of f-tiles
#define FCH 50     // f's per tile (FT*FCH == NF)

// Static device scratch.
__device__ float g_P_sp[NB * NF];
__device__ float g_P_po[NB * NF];
__device__ float g_e2[NN];
// layout: [s][b][slot][n]  -> coalesced writes (main) and reads (finalize)
__device__ float g_part[2 * NB * FT * NN];

// One block per 256 f's; each thread owns one f, loops k, accumulates all 8 b's.
// P_sp[b][f] = ||fact||^2 + ||rel_b||^2 + ||arg1_b||^2 - 2*(rel_b.frel_f + arg1_b.farg1_f)
__global__ void precompute_P(const float* __restrict__ rel,
                             const float* __restrict__ arg1,
                             const float* __restrict__ arg2,
                             const float* __restrict__ frel,
                             const float* __restrict__ fa1,
                             const float* __restrict__ fa2) {
    int f = blockIdx.x * blockDim.x + threadIdx.x;
    if (f >= NF) return;
    float nf = 0.f;
    float dr[NB], d1[NB], d2[NB];
    #pragma unroll
    for (int b = 0; b < NB; b++) { dr[b] = 0.f; d1[b] = 0.f; d2[b] = 0.f; }
    for (int k = 0; k < EDIM; k++) {
        float vr = frel[f * EDIM + k];
        float v1 = fa1[f * EDIM + k];
        float v2 = fa2[f * EDIM + k];
        nf += vr * vr + v1 * v1 + v2 * v2;
        #pragma unroll
        for (int b = 0; b < NB; b++) {
            dr[b] = fmaf(rel[b * EDIM + k], vr, dr[b]);   // wave-uniform scalar loads
            d1[b] = fmaf(arg1[b * EDIM + k], v1, d1[b]);
            d2[b] = fmaf(arg2[b * EDIM + k], v2, d2[b]);
        }
    }
    #pragma unroll
    for (int b = 0; b < NB; b++) {
        float qr = 0.f, q1 = 0.f, q2 = 0.f;
        for (int k = 0; k < EDIM; k++) {
            float rb = rel[b * EDIM + k];
            float a1 = arg1[b * EDIM + k];
            float a2 = arg2[b * EDIM + k];
            qr = fmaf(rb, rb, qr);
            q1 = fmaf(a1, a1, q1);
            q2 = fmaf(a2, a2, q2);
        }
        g_P_sp[b * NF + f] = nf + qr + q1 - 2.f * (dr[b] + d1[b]);
        g_P_po[b * NF + f] = nf + qr + q2 - 2.f * (dr[b] + d2[b]);
    }
}

__global__ void precompute_e2(const float* __restrict__ ent) {
    int n = blockIdx.x * blockDim.x + threadIdx.x;
    if (n >= NN) return;
    const float4* ep = (const float4*)(ent + n * EDIM);
    float s = 0.f;
    #pragma unroll
    for (int i = 0; i < EDIM / 4; i++) {
        float4 v = ep[i];
        s += v.x * v.x + v.y * v.y + v.z * v.z + v.w * v.w;
    }
    g_e2[n] = s;
}

// Thread-per-n; e[] register-resident (launch_bounds relaxes VGPR cap).
__global__ void __launch_bounds__(256, 3) main_kernel(const float* __restrict__ ent,
                                                      const float* __restrict__ fa1,
                                                      const float* __restrict__ fa2) {
    int n = blockIdx.x * 256 + threadIdx.x;
    if (n >= NN) return;

    float e[EDIM];
    const float4* ep = (const float4*)(ent + n * EDIM);
    #pragma unroll
    for (int i = 0; i < EDIM / 4; i++) {
        float4 v = ep[i];
        e[4 * i + 0] = v.x; e[4 * i + 1] = v.y;
        e[4 * i + 2] = v.z; e[4 * i + 3] = v.w;
    }

    float msp[NB], mpo[NB];
    #pragma unroll
    for (int b = 0; b < NB; b++) { msp[b] = INFINITY; mpo[b] = INFINITY; }

    const int f0 = blockIdx.y * FCH;
    for (int ff = 0; ff < FCH; ff++) {
        const int f = f0 + ff;
        const float4* p1 = (const float4*)(fa1 + f * EDIM);
        const float4* p2 = (const float4*)(fa2 + f * EDIM);
        float g1 = 0.f, g2 = 0.f;
        #pragma unroll
        for (int i = 0; i < EDIM / 4; i++) {
            float4 a = p1[i];
            float4 c = p2[i];
            g1 = fmaf(e[4 * i + 0], a.x, g1);
            g1 = fmaf(e[4 * i + 1], a.y, g1);
            g1 = fmaf(e[4 * i + 2], a.z, g1);
            g1 = fmaf(e[4 * i + 3], a.w, g1);
            g2 = fmaf(e[4 * i + 0], c.x, g2);
            g2 = fmaf(e[4 * i + 1], c.y, g2);
            g2 = fmaf(e[4 * i + 2], c.z, g2);
            g2 = fmaf(e[4 * i + 3], c.w, g2);
        }
        // score_sp pairs with ent.fact_arg2 (g2); score_po with ent.fact_arg1 (g1)
        #pragma unroll
        for (int b = 0; b < NB; b++) {
            msp[b] = fminf(msp[b], fmaf(-2.f, g2, g_P_sp[b * NF + f]));
            mpo[b] = fminf(mpo[b], fmaf(-2.f, g1, g_P_po[b * NF + f]));
        }
    }

    const int slot = blockIdx.y;
    #pragma unroll
    for (int b = 0; b < NB; b++) {
        g_part[((0 * NB + b) * FT + slot) * NN + n] = msp[b];
        g_part[((1 * NB + b) * FT + slot) * NN + n] = mpo[b];
    }
}

__global__ void finalize(float* __restrict__ out) {
    int idx = blockIdx.x * 256 + threadIdx.x;  // over 2*NB*NN, == out layout (s*B+b)*N+n
    if (idx >= 2 * NB * NN) return;
    int sb = idx / NN;
    int n = idx % NN;
    float m = INFINITY;
    #pragma unroll 8
    for (int j = 0; j < FT; j++) m = fminf(m, g_part[(sb * FT + j) * NN + n]);
    float d2 = fmaxf(m + g_e2[n], 0.f);
    out[idx] = expf(-0.5f * d2);
}

extern "C" void kernel_launch(void* const* d_in, const int* in_sizes, int n_in,
                              void* d_out, int out_size, void* d_ws, size_t ws_size,
                              hipStream_t stream) {
    const float* rel  = (const float*)d_in[0];
    const float* arg1 = (const float*)d_in[1];
    const float* arg2 = (const float*)d_in[2];
    const float* frel = (const float*)d_in[3];
    const float* fa1  = (const float*)d_in[4];
    const float* fa2  = (const float*)d_in[5];
    const float* ent  = (const float*)d_in[6];
    float* out = (float*)d_out;

    precompute_P<<<(NF + 255) / 256, 256, 0, stream>>>(rel, arg1, arg2, frel, fa1, fa2);
    precompute_e2<<<(NN + 255) / 256, 256, 0, stream>>>(ent);
    main_kernel<<<dim3((NN + 255) / 256, FT), 256, 0, stream>>>(ent, fa1, fa2);
    finalize<<<(2 * NB * NN + 255) / 256, 256, 0, stream>>>(out);
}

// Round 3
// 207.066 us; speedup vs baseline: 1.7588x; 1.7588x over previous
//
#include <hip/hip_runtime.h>
#include <math.h>

#define EDIM 100
#define KP   128          // padded K
#define NF   4000
#define NN   4000
#define NB   8
#define NP   4096         // padded N and F
#define BN   128          // n-rows per block
#define BF   64           // f-cols per block
#define NFB  (NP / BF)    // 64 f-blocks

typedef __attribute__((ext_vector_type(8))) short short8;
typedef __attribute__((ext_vector_type(4))) float floatx4;

// Static device scratch.
__device__ __align__(16) unsigned short g_A [NP * KP];   // ent  bf16, K-padded
__device__ __align__(16) unsigned short g_B1[NP * KP];   // fa1  bf16
__device__ __align__(16) unsigned short g_B2[NP * KP];   // fa2  bf16
__device__ __align__(16) float g_P[2 * NB * NP];         // [g][b][f], +INF on f-pad
__device__ float g_e2[NN];
__device__ float g_part[2 * NB * NFB * NP];              // [g][b][fblk][n]

__device__ __forceinline__ unsigned short f2bf(float x) {
    union { float f; unsigned int u; } v; v.f = x;
    unsigned int r = v.u + 0x7FFFu + ((v.u >> 16) & 1u);  // RNE
    return (unsigned short)(r >> 16);
}

// Convert fp32 [4000][100] -> bf16 [4096][128] zero-padded. y picks matrix.
__global__ void convert(const float* __restrict__ ent,
                        const float* __restrict__ fa1,
                        const float* __restrict__ fa2) {
    int idx = blockIdx.x * 256 + threadIdx.x;       // over NP*KP
    const float* src = (blockIdx.y == 0) ? ent : (blockIdx.y == 1) ? fa1 : fa2;
    unsigned short* dst = (blockIdx.y == 0) ? g_A : (blockIdx.y == 1) ? g_B1 : g_B2;
    int row = idx >> 7, k = idx & (KP - 1);
    float v = (row < NF && k < EDIM) ? src[row * EDIM + k] : 0.f;
    dst[idx] = f2bf(v);
}

// P[0][b][f] = ||fact||^2 + ||rel_b||^2 + ||arg1_b||^2 - 2*(rel_b.frel + arg1_b.fa1)
// P[1][b][f] = same with arg2/fa2.  f>=NF -> +INF.
__global__ void precompute_P(const float* __restrict__ rel,
                             const float* __restrict__ arg1,
                             const float* __restrict__ arg2,
                             const float* __restrict__ frel,
                             const float* __restrict__ fa1,
                             const float* __restrict__ fa2) {
    int f = blockIdx.x * 256 + threadIdx.x;
    int b = blockIdx.y;
    if (f >= NP) return;
    if (f >= NF) {
        g_P[(0 * NB + b) * NP + f] = __builtin_inff();
        g_P[(1 * NB + b) * NP + f] = __builtin_inff();
        return;
    }
    float nf = 0.f, dr = 0.f, d1 = 0.f, d2 = 0.f, qr = 0.f, q1 = 0.f, q2 = 0.f;
    for (int k = 0; k < EDIM; k++) {
        float vr = frel[f * EDIM + k];
        float v1 = fa1[f * EDIM + k];
        float v2 = fa2[f * EDIM + k];
        float rb = rel[b * EDIM + k];     // wave-uniform
        float a1 = arg1[b * EDIM + k];
        float a2 = arg2[b * EDIM + k];
        nf += vr * vr + v1 * v1 + v2 * v2;
        dr = fmaf(rb, vr, dr);
        d1 = fmaf(a1, v1, d1);
        d2 = fmaf(a2, v2, d2);
        qr = fmaf(rb, rb, qr);
        q1 = fmaf(a1, a1, q1);
        q2 = fmaf(a2, a2, q2);
    }
    g_P[(0 * NB + b) * NP + f] = nf + qr + q1 - 2.f * (dr + d1);
    g_P[(1 * NB + b) * NP + f] = nf + qr + q2 - 2.f * (dr + d2);
}

__global__ void precompute_e2(const float* __restrict__ ent) {
    int n = blockIdx.x * 256 + threadIdx.x;
    if (n >= NN) return;
    const float4* ep = (const float4*)(ent + n * EDIM);
    float s = 0.f;
    #pragma unroll
    for (int i = 0; i < EDIM / 4; i++) {
        float4 v = ep[i];
        s += v.x * v.x + v.y * v.y + v.z * v.z + v.w * v.w;
    }
    g_e2[n] = s;
}

// Main: 128n x 64f tile, K=128 in one shot (no K-loop). bf16 MFMA 16x16x32.
// acc[g][mt][ft]; g=0: score_sp pairs with fa2 (B2); g=1: score_po with fa1 (B1).
__global__ void __launch_bounds__(256, 2) main_kernel() {
    __shared__ float4 lA4 [BN * 16];     // 128 rows x 16 chunks(16B)  = 32 KB
    __shared__ float4 lB14[BF * 16];     //  64 rows x 16 chunks       = 16 KB
    __shared__ float4 lB24[BF * 16];     //  16 KB
    __shared__ float  lP  [2 * NB * BF]; //   4 KB

    const int t = threadIdx.x;
    const int n0 = blockIdx.x * BN;
    const int fblk = blockIdx.y;
    const int f0 = fblk * BF;

    // ---- stage: contiguous global float4 -> LDS with XOR chunk swizzle ----
    const float4* gA4 = (const float4*)g_A;    // chunk = 8 bf16 = 16 B; 16 chunks/row
    const float4* gB14 = (const float4*)g_B1;
    const float4* gB24 = (const float4*)g_B2;
    #pragma unroll
    for (int i = 0; i < 8; i++) {              // A: 128 rows * 16 chunks / 256 thr
        int gc = i * 256 + t;
        int row = gc >> 4, ch = gc & 15;
        lA4[row * 16 + (ch ^ (row & 15))] = gA4[n0 * 16 + gc];
    }
    #pragma unroll
    for (int i = 0; i < 4; i++) {              // B: 64 rows * 16 chunks / 256 thr
        int gc = i * 256 + t;
        int row = gc >> 4, ch = gc & 15;
        int sl = row * 16 + (ch ^ (row & 15));
        lB14[sl] = gB14[f0 * 16 + gc];
        lB24[sl] = gB24[f0 * 16 + gc];
    }
    {                                          // P: 16 sb-rows * 64 f = 256 float4
        int sb = t >> 4, fc = t & 15;
        ((float4*)lP)[t] = ((const float4*)g_P)[sb * (NP / 4) + (f0 >> 2) + fc];
    }
    __syncthreads();

    // ---- MFMA phase ----
    const int lane = t & 63;
    const int c = lane & 15;         // col-of-tile / row index mod 16
    const int q = lane >> 4;         // quad
    const int w = t >> 6;            // wave id 0..3
    const int w32 = w * 32;          // this wave's first n-row (local)

    const short8* pA  = (const short8*)lA4;
    const short8* pB1 = (const short8*)lB14;
    const short8* pB2 = (const short8*)lB24;

    floatx4 acc[2][2][4];            // [g][mt][ft]
    #pragma unroll
    for (int g = 0; g < 2; g++)
        #pragma unroll
        for (int mt = 0; mt < 2; mt++)
            #pragma unroll
            for (int ft = 0; ft < 4; ft++)
                acc[g][mt][ft] = (floatx4){0.f, 0.f, 0.f, 0.f};

    #pragma unroll
    for (int s = 0; s < 4; s++) {    // K-steps of 32
        const int base = s * 4 + q;
        short8 a0 = pA[(w32 + c) * 16 + (base ^ c)];
        short8 a1 = pA[(w32 + 16 + c) * 16 + (base ^ c)];
        #pragma unroll
        for (int ft = 0; ft < 4; ft++) {
            int sl = (ft * 16 + c) * 16 + (base ^ c);
            short8 b1 = pB1[sl];
            short8 b2 = pB2[sl];
            acc[0][0][ft] = __builtin_amdgcn_mfma_f32_16x16x32_bf16(a0, b2, acc[0][0][ft], 0, 0, 0);
            acc[0][1][ft] = __builtin_amdgcn_mfma_f32_16x16x32_bf16(a1, b2, acc[0][1][ft], 0, 0, 0);
            acc[1][0][ft] = __builtin_amdgcn_mfma_f32_16x16x32_bf16(a0, b1, acc[1][0][ft], 0, 0, 0);
            acc[1][1][ft] = __builtin_amdgcn_mfma_f32_16x16x32_bf16(a1, b1, acc[1][1][ft], 0, 0, 0);
        }
    }

    // ---- fused epilogue: msp/mpo[b][n] = min_f (P[b][f] - 2*G[n][f]) ----
    // C layout: col(f) = c, row(n-local) = q*4 + r.
    #pragma unroll
    for (int g = 0; g < 2; g++) {
        float pr[NB][4];                       // P[g][b][ft*16 + c]
        #pragma unroll
        for (int b = 0; b < NB; b++)
            #pragma unroll
            for (int ft = 0; ft < 4; ft++)
                pr[b][ft] = lP[(g * NB + b) * BF + ft * 16 + c];
        #pragma unroll
        for (int mt = 0; mt < 2; mt++)
            #pragma unroll
            for (int r = 0; r < 4; r++) {
                int n = n0 + w32 + mt * 16 + q * 4 + r;
                #pragma unroll
                for (int b = 0; b < NB; b++) {
                    float v =          fmaf(-2.f, acc[g][mt][0][r], pr[b][0]);
                    v = fminf(v, fmaf(-2.f, acc[g][mt][1][r], pr[b][1]));
                    v = fminf(v, fmaf(-2.f, acc[g][mt][2][r], pr[b][2]));
                    v = fminf(v, fmaf(-2.f, acc[g][mt][3][r], pr[b][3]));
                    v = fminf(v, __shfl_xor(v, 1));
                    v = fminf(v, __shfl_xor(v, 2));
                    v = fminf(v, __shfl_xor(v, 4));
                    v = fminf(v, __shfl_xor(v, 8));
                    if (c == b)
                        g_part[((g * NB + b) * NFB + fblk) * NP + n] = v;
                }
            }
    }
}

__global__ void finalize(float* __restrict__ out) {
    int idx = blockIdx.x * 256 + threadIdx.x;   // over 2*NB*NN, out layout (g*NB+b)*NN+n
    if (idx >= 2 * NB * NN) return;
    int sb = idx / NN;
    int n = idx % NN;
    float m = __builtin_inff();
    #pragma unroll 8
    for (int j = 0; j < NFB; j++) m = fminf(m, g_part[(sb * NFB + j) * NP + n]);
    float d2 = fmaxf(m + g_e2[n], 0.f);
    out[idx] = expf(-0.5f * d2);
}

extern "C" void kernel_launch(void* const* d_in, const int* in_sizes, int n_in,
                              void* d_out, int out_size, void* d_ws, size_t ws_size,
                              hipStream_t stream) {
    const float* rel  = (const float*)d_in[0];
    const float* arg1 = (const float*)d_in[1];
    const float* arg2 = (const float*)d_in[2];
    const float* frel = (const float*)d_in[3];
    const float* fa1  = (const float*)d_in[4];
    const float* fa2  = (const float*)d_in[5];
    const float* ent  = (const float*)d_in[6];
    float* out = (float*)d_out;

    convert<<<dim3(NP * KP / 256, 3), 256, 0, stream>>>(ent, fa1, fa2);
    precompute_P<<<dim3(NP / 256, NB), 256, 0, stream>>>(rel, arg1, arg2, frel, fa1, fa2);
    precompute_e2<<<(NN + 255) / 256, 256, 0, stream>>>(ent);
    main_kernel<<<dim3(NP / BN, NFB), 256, 0, stream>>>();
    finalize<<<(2 * NB * NN + 255) / 256, 256, 0, stream>>>(out);
}

// Round 4
// 136.221 us; speedup vs baseline: 2.6736x; 1.5201x over previous
//
#include <hip/hip_runtime.h>
#include <math.h>

#define EDIM 100
#define KP   128          // padded K
#define NF   4000
#define NN   4000
#define NB   8
#define NP   4096         // padded N and F
#define BN   128          // n-rows per block
#define BF   64           // f-cols per block
#define NFB  (NP / BF)    // 64 f-blocks
#define TRS  68           // transpose row stride (floats): 64 + 4 pad, 16B-aligned

typedef __attribute__((ext_vector_type(8))) short short8;
typedef __attribute__((ext_vector_type(4))) float floatx4;

// Static device scratch.
__device__ __align__(16) unsigned short g_A [NP * KP];   // ent  bf16, K-padded
__device__ __align__(16) unsigned short g_B1[NP * KP];   // fa1  bf16
__device__ __align__(16) unsigned short g_B2[NP * KP];   // fa2  bf16
__device__ __align__(16) float g_P[2 * NB * NP];         // [g][b][f], +INF on f-pad
__device__ float g_e2[NN];
__device__ float g_part[2 * NB * NFB * NP];              // [g][b][fblk][n]

__device__ __forceinline__ unsigned short f2bf(float x) {
    union { float f; unsigned int u; } v; v.f = x;
    unsigned int r = v.u + 0x7FFFu + ((v.u >> 16) & 1u);  // RNE
    return (unsigned short)(r >> 16);
}

// Convert fp32 [4000][100] -> bf16 [4096][128] zero-padded. y picks matrix.
__global__ void convert(const float* __restrict__ ent,
                        const float* __restrict__ fa1,
                        const float* __restrict__ fa2) {
    int idx = blockIdx.x * 256 + threadIdx.x;       // over NP*KP
    const float* src = (blockIdx.y == 0) ? ent : (blockIdx.y == 1) ? fa1 : fa2;
    unsigned short* dst = (blockIdx.y == 0) ? g_A : (blockIdx.y == 1) ? g_B1 : g_B2;
    int row = idx >> 7, k = idx & (KP - 1);
    float v = (row < NF && k < EDIM) ? src[row * EDIM + k] : 0.f;
    dst[idx] = f2bf(v);
}

// One wave per 16 f's; lanes = (f_local 16) x (k-quarter 4); shfl-reduce k-quarters.
// P[0][b][f] = ||fact||^2 + ||rel_b||^2 + ||arg1_b||^2 - 2*(rel_b.frel + arg1_b.fa1)
// P[1][b][f] = same with arg2/fa2.  f>=NF -> +INF.
__global__ void precompute_P(const float* __restrict__ rel,
                             const float* __restrict__ arg1,
                             const float* __restrict__ arg2,
                             const float* __restrict__ frel,
                             const float* __restrict__ fa1,
                             const float* __restrict__ fa2) {
    const int t = threadIdx.x;          // 64 threads
    const int fl = t & 15;
    const int kq = t >> 4;              // 0..3
    const int f = blockIdx.x * 16 + fl;
    const int b = blockIdx.y;
    const int fr = (f < NF) ? f : (NF - 1);   // clamp to stay in-bounds; pad overwritten below

    float nf = 0.f, dr = 0.f, d1 = 0.f, d2 = 0.f, qr = 0.f, q1 = 0.f, q2 = 0.f;
    for (int i = 0; i < 25; i++) {
        int k = kq * 25 + i;
        float vr = frel[fr * EDIM + k];
        float v1 = fa1[fr * EDIM + k];
        float v2 = fa2[fr * EDIM + k];
        float rb = rel[b * EDIM + k];        // wave-uniform -> s_load
        float a1 = arg1[b * EDIM + k];
        float a2 = arg2[b * EDIM + k];
        nf += vr * vr + v1 * v1 + v2 * v2;
        dr = fmaf(rb, vr, dr);
        d1 = fmaf(a1, v1, d1);
        d2 = fmaf(a2, v2, d2);
        qr = fmaf(rb, rb, qr);
        q1 = fmaf(a1, a1, q1);
        q2 = fmaf(a2, a2, q2);
    }
    // reduce over k-quarters (lanes xor 16, 32)
    nf += __shfl_xor(nf, 16); nf += __shfl_xor(nf, 32);
    dr += __shfl_xor(dr, 16); dr += __shfl_xor(dr, 32);
    d1 += __shfl_xor(d1, 16); d1 += __shfl_xor(d1, 32);
    d2 += __shfl_xor(d2, 16); d2 += __shfl_xor(d2, 32);
    qr += __shfl_xor(qr, 16); qr += __shfl_xor(qr, 32);
    q1 += __shfl_xor(q1, 16); q1 += __shfl_xor(q1, 32);
    q2 += __shfl_xor(q2, 16); q2 += __shfl_xor(q2, 32);
    if (kq == 0) {
        float psp = nf + qr + q1 - 2.f * (dr + d1);
        float ppo = nf + qr + q2 - 2.f * (dr + d2);
        if (f >= NF) { psp = __builtin_inff(); ppo = __builtin_inff(); }
        g_P[(0 * NB + b) * NP + f] = psp;
        g_P[(1 * NB + b) * NP + f] = ppo;
    }
}

__global__ void precompute_e2(const float* __restrict__ ent) {
    int n = blockIdx.x * 256 + threadIdx.x;
    if (n >= NN) return;
    const float4* ep = (const float4*)(ent + n * EDIM);
    float s = 0.f;
    #pragma unroll
    for (int i = 0; i < EDIM / 4; i++) {
        float4 v = ep[i];
        s += v.x * v.x + v.y * v.y + v.z * v.z + v.w * v.w;
    }
    g_e2[n] = s;
}

// Main: 128n x 64f tile, K=128 in one shot. bf16 MFMA 16x16x32.
// Epilogue: LDS transpose of G (reusing staging LDS), then per-(g,row) thread
// folds P (scalar loads) + min over all 64 f's in registers.
__global__ void __launch_bounds__(256, 2) main_kernel() {
    __shared__ float4 smem4[4352];          // 69632 B
    float4* lA4  = smem4;                   // 32 KB: A 128 rows x 16 chunks
    float4* lB14 = smem4 + 2048;            // 16 KB
    float4* lB24 = smem4 + 3072;            // 16 KB
    float*  tr   = (float*)smem4;           // reuse: [2][128][TRS] = 69632 B

    const int t = threadIdx.x;
    const int n0 = blockIdx.x * BN;
    const int fblk = blockIdx.y;
    const int f0 = fblk * BF;

    // ---- stage: contiguous global float4 -> LDS with XOR chunk swizzle ----
    const float4* gA4 = (const float4*)g_A;
    const float4* gB14 = (const float4*)g_B1;
    const float4* gB24 = (const float4*)g_B2;
    #pragma unroll
    for (int i = 0; i < 8; i++) {
        int gc = i * 256 + t;
        int row = gc >> 4, ch = gc & 15;
        lA4[row * 16 + (ch ^ (row & 15))] = gA4[n0 * 16 + gc];
    }
    #pragma unroll
    for (int i = 0; i < 4; i++) {
        int gc = i * 256 + t;
        int row = gc >> 4, ch = gc & 15;
        int sl = row * 16 + (ch ^ (row & 15));
        lB14[sl] = gB14[f0 * 16 + gc];
        lB24[sl] = gB24[f0 * 16 + gc];
    }
    __syncthreads();

    // ---- MFMA phase ----
    const int lane = t & 63;
    const int c = lane & 15;
    const int q = lane >> 4;
    const int w = t >> 6;
    const int w32 = w * 32;

    const short8* pA  = (const short8*)lA4;
    const short8* pB1 = (const short8*)lB14;
    const short8* pB2 = (const short8*)lB24;

    floatx4 acc[2][2][4];                   // [g][mt][ft]
    #pragma unroll
    for (int g = 0; g < 2; g++)
        #pragma unroll
        for (int mt = 0; mt < 2; mt++)
            #pragma unroll
            for (int ft = 0; ft < 4; ft++)
                acc[g][mt][ft] = (floatx4){0.f, 0.f, 0.f, 0.f};

    #pragma unroll
    for (int s = 0; s < 4; s++) {           // K-steps of 32
        const int base = s * 4 + q;
        short8 a0 = pA[(w32 + c) * 16 + (base ^ c)];
        short8 a1 = pA[(w32 + 16 + c) * 16 + (base ^ c)];
        #pragma unroll
        for (int ft = 0; ft < 4; ft++) {
            int sl = (ft * 16 + c) * 16 + (base ^ c);
            short8 b1 = pB1[sl];
            short8 b2 = pB2[sl];
            acc[0][0][ft] = __builtin_amdgcn_mfma_f32_16x16x32_bf16(a0, b2, acc[0][0][ft], 0, 0, 0);
            acc[0][1][ft] = __builtin_amdgcn_mfma_f32_16x16x32_bf16(a1, b2, acc[0][1][ft], 0, 0, 0);
            acc[1][0][ft] = __builtin_amdgcn_mfma_f32_16x16x32_bf16(a0, b1, acc[1][0][ft], 0, 0, 0);
            acc[1][1][ft] = __builtin_amdgcn_mfma_f32_16x16x32_bf16(a1, b1, acc[1][1][ft], 0, 0, 0);
        }
    }

    __syncthreads();   // all frag reads done; staging LDS now reusable

    // ---- transpose G -> tr[g][row][f].  C layout: col(f)=c, row(n)=q*4+r.
    // Banks: (272q + c) % 32 -> 2 lanes/bank max = free.
    #pragma unroll
    for (int g = 0; g < 2; g++)
        #pragma unroll
        for (int mt = 0; mt < 2; mt++)
            #pragma unroll
            for (int ft = 0; ft < 4; ft++)
                #pragma unroll
                for (int r = 0; r < 4; r++)
                    tr[(g * BN + w32 + mt * 16 + q * 4 + r) * TRS + ft * 16 + c] =
                        acc[g][mt][ft][r];
    __syncthreads();

    // ---- phase 2: thread owns (g,row); min over 64 f's with P via s_load ----
    const int g2 = t >> 7;                  // uniform per wave
    const int row = t & 127;
    const float4* trg = (const float4*)(tr + (g2 * BN + row) * TRS);
    float4 G4[16];
    #pragma unroll
    for (int ch = 0; ch < 16; ch++) G4[ch] = trg[ch];

    #pragma unroll
    for (int b = 0; b < NB; b++) {
        const float4* Pp = (const float4*)(g_P + (g2 * NB + b) * NP + f0);  // wave-uniform
        float4 m4 = {__builtin_inff(), __builtin_inff(), __builtin_inff(), __builtin_inff()};
        #pragma unroll
        for (int ch = 0; ch < 16; ch++) {
            float4 p = Pp[ch];
            m4.x = fminf(m4.x, fmaf(-2.f, G4[ch].x, p.x));
            m4.y = fminf(m4.y, fmaf(-2.f, G4[ch].y, p.y));
            m4.z = fminf(m4.z, fmaf(-2.f, G4[ch].z, p.z));
            m4.w = fminf(m4.w, fmaf(-2.f, G4[ch].w, p.w));
        }
        float m = fminf(fminf(m4.x, m4.y), fminf(m4.z, m4.w));
        g_part[((g2 * NB + b) * NFB + fblk) * NP + n0 + row] = m;
    }
}

__global__ void finalize(float* __restrict__ out) {
    int idx = blockIdx.x * 256 + threadIdx.x;   // over 2*NB*NN, out layout (g*NB+b)*NN+n
    if (idx >= 2 * NB * NN) return;
    int sb = idx / NN;
    int n = idx % NN;
    float m = __builtin_inff();
    #pragma unroll 8
    for (int j = 0; j < NFB; j++) m = fminf(m, g_part[(sb * NFB + j) * NP + n]);
    float d2 = fmaxf(m + g_e2[n], 0.f);
    out[idx] = expf(-0.5f * d2);
}

extern "C" void kernel_launch(void* const* d_in, const int* in_sizes, int n_in,
                              void* d_out, int out_size, void* d_ws, size_t ws_size,
                              hipStream_t stream) {
    const float* rel  = (const float*)d_in[0];
    const float* arg1 = (const float*)d_in[1];
    const float* arg2 = (const float*)d_in[2];
    const float* frel = (const float*)d_in[3];
    const float* fa1  = (const float*)d_in[4];
    const float* fa2  = (const float*)d_in[5];
    const float* ent  = (const float*)d_in[6];
    float* out = (float*)d_out;

    convert<<<dim3(NP * KP / 256, 3), 256, 0, stream>>>(ent, fa1, fa2);
    precompute_P<<<dim3(NP / 16, NB), 64, 0, stream>>>(rel, arg1, arg2, frel, fa1, fa2);
    precompute_e2<<<(NN + 255) / 256, 256, 0, stream>>>(ent);
    main_kernel<<<dim3(NP / BN, NFB), 256, 0, stream>>>();
    finalize<<<(2 * NB * NN + 255) / 256, 256, 0, stream>>>(out);
}